// Round 1
// 102.453 us; speedup vs baseline: 1.0654x; 1.0654x over previous
//
#include <hip/hip_runtime.h>
#include <math.h>

#define Bv 4
#define Nv 512
#define Dv 128
#define BND (Bv*Nv*Dv)      // 262144
#define NN  (Nv*Nv)         // 262144
#define EPSv 1e-9f

typedef float f4 __attribute__((ext_vector_type(4)));

__device__ __forceinline__ f4 relu4(f4 z) {
#if __has_builtin(__builtin_elementwise_max)
    return __builtin_elementwise_max(z, (f4)0.0f);
#else
    z.x = fmaxf(z.x, 0.0f); z.y = fmaxf(z.y, 0.0f);
    z.z = fmaxf(z.z, 0.0f); z.w = fmaxf(z.w, 0.0f);
    return z;
#endif
}

// -------------------------------------------------------------------------
// k_prep: (a) gumbel-softmax row bi -> 4 batch copies of A; (b) proj =
// ES@Wp+bp for 4 rows; (c) s'/t. Grid 512 -> 2 blocks/CU (8 waves/CU).
// R5 change: precise logf/expf -> __logf/__expf (v_log/v_exp path). A
// perturbation ~1e-5 relative, tolerance is 7.8e-3 absolute.
// -------------------------------------------------------------------------
__global__ __launch_bounds__(256) void k_prep(
    const float* __restrict__ ES, const float* __restrict__ Wp,
    const float* __restrict__ bp, const float* __restrict__ W1,
    const float* __restrict__ b1, const float* __restrict__ EL,
    const float* __restrict__ UN,
    float* __restrict__ s_out, float* __restrict__ t_out,
    float* __restrict__ A_out)
{
    __shared__ float es[4][Dv];
    __shared__ float pr[4][Dv];
    __shared__ float sred[4];
    const int bi = blockIdx.x;        // 0..511
    const int t  = threadIdx.x;

    // ---- phase A: softmax((EL+gumbel)/TAU) for row bi, broadcast to 4 b's
    {
        const int row = bi;
        const float u0 = UN[row*Nv + t];
        const float u1 = UN[row*Nv + t + 256];
        const float g0 = -__logf(-__logf(u0 + EPSv) + EPSv);
        const float g1 = -__logf(-__logf(u1 + EPSv) + EPSv);
        const float z0 = (EL[row*Nv + t]       + g0) * 2.0f;   // 1/TAU = 2
        const float z1 = (EL[row*Nv + t + 256] + g1) * 2.0f;

        float m = fmaxf(z0, z1);
        #pragma unroll
        for (int off = 32; off >= 1; off >>= 1)
            m = fmaxf(m, __shfl_xor(m, off, 64));
        if ((t & 63) == 0) sred[t >> 6] = m;
        __syncthreads();
        m = fmaxf(fmaxf(sred[0], sred[1]), fmaxf(sred[2], sred[3]));

        const float e0 = __expf(z0 - m);
        const float e1 = __expf(z1 - m);
        float ssum = e0 + e1;
        #pragma unroll
        for (int off = 32; off >= 1; off >>= 1)
            ssum += __shfl_xor(ssum, off, 64);
        __syncthreads();
        if ((t & 63) == 0) sred[t >> 6] = ssum;
        __syncthreads();
        const float inv = 1.0f / (sred[0] + sred[1] + sred[2] + sred[3]);
        const float a0 = e0 * inv;
        const float a1 = e1 * inv;
        #pragma unroll
        for (int bb = 0; bb < Bv; ++bb) {
            A_out[bb*NN + row*Nv + t]       = a0;
            A_out[bb*NN + row*Nv + t + 256] = a1;
        }
    }

    // ---- phase B: proj for rows bi*4 .. bi*4+3
    const int row0 = bi * 4;
    const int c  = t & 127;
    const int rg = t >> 7;            // 0..1 -> rows rg*2, rg*2+1

    for (int idx = t; idx < 4*Dv; idx += 256)
        es[idx >> 7][idx & 127] = ES[(row0 + (idx >> 7))*Dv + (idx & 127)];
    __syncthreads();

    {
        float acc[2];
        const float bpc = bp[c];
        acc[0] = bpc; acc[1] = bpc;
        #pragma unroll 8
        for (int k = 0; k < Dv; ++k) {
            const float w = Wp[k*Dv + c];
            acc[0] = fmaf(es[rg*2][k],   w, acc[0]);
            acc[1] = fmaf(es[rg*2+1][k], w, acc[1]);
        }
        pr[rg*2][c]   = acc[0];
        pr[rg*2+1][c] = acc[1];
    }
    __syncthreads();

    // ---- phase C: s' = proj@W1_src + b1, t = proj@W1_tgt
    float sacc0 = b1[c], sacc1 = sacc0, tacc0 = 0.0f, tacc1 = 0.0f;
    #pragma unroll 8
    for (int k = 0; k < Dv; ++k) {
        const float ws_ = W1[k*Dv + c];
        const float wt_ = W1[(Dv + k)*Dv + c];
        const float p0 = pr[rg*2][k];
        const float p1 = pr[rg*2+1][k];
        sacc0 = fmaf(p0, ws_, sacc0);
        sacc1 = fmaf(p1, ws_, sacc1);
        tacc0 = fmaf(p0, wt_, tacc0);
        tacc1 = fmaf(p1, wt_, tacc1);
    }
    const int ra = (row0 + rg*2)*Dv + c;
    s_out[ra]      = sacc0;
    s_out[ra + Dv] = sacc1;
    t_out[ra]      = tacc0;
    t_out[ra + Dv] = tacc1;
}

// -------------------------------------------------------------------------
// k_main R5: block = (8 i-rows, b), grid (64,4)=256 blocks, but now
// 512 threads/block -> 8 waves/CU = 2 waves/SIMD (was 1 wave/SIMD: zero
// inter-wave latency hiding was the stall source; VALU floor is ~5 us).
// Thread = (d-quad dq, j-group jg of 32 js). Explicit 1-iteration-ahead
// sv prefetch (peeled tail keeps the guard compile-time under full unroll).
// LDS: A 16K + part 64K + hsum 4K = 84 KB (<160, 1 block/CU).
// __launch_bounds__(512,2) caps VGPR at 256 so all 8 waves stay resident.
// -------------------------------------------------------------------------
__global__ __launch_bounds__(512, 2) void k_main(
    const float* __restrict__ s_buf, const float* __restrict__ t_buf,
    const float* __restrict__ A0,    const float* __restrict__ ES,
    const float* __restrict__ W2,    const float* __restrict__ b2,
    float* __restrict__ out)
{
    __shared__ float A_lds[8][Nv];     // 16 KB
    __shared__ f4    part[16][8][32];  // 64 KB [jg][i][dq]
    __shared__ float hsum[8][Dv];      // 4 KB
    const int i0 = blockIdx.x * 8;
    const int b  = blockIdx.y;
    const int t  = threadIdx.x;
    const int dq = t & 31;             // d = dq*4 .. dq*4+3
    const int jg = t >> 5;             // 0..15 -> j in [jg*32, jg*32+32)

    // stage A rows i0..i0+7 (b-independent copy 0), coalesced f4
    {
        const f4* __restrict__ src = (const f4*)(A0 + i0*Nv);
        f4* dst = (f4*)(&A_lds[0][0]);
        dst[t]       = src[t];
        dst[t + 512] = src[t + 512];
    }

    f4 tv[8];
    #pragma unroll
    for (int r = 0; r < 8; ++r)
        tv[r] = *(const f4*)(t_buf + (b*Nv + i0 + r)*Dv + dq*4);

    f4 acc[8];
    #pragma unroll
    for (int r = 0; r < 8; ++r) acc[r] = (f4)0.0f;

    __syncthreads();                   // A_lds ready

    const float* __restrict__ sb = s_buf + (size_t)b*Nv*Dv + dq*4;
    const int j0 = jg * 32;

    // prefetch first j4 quad
    f4 svn0 = *(const f4*)(sb + (j0+0)*Dv);
    f4 svn1 = *(const f4*)(sb + (j0+1)*Dv);
    f4 svn2 = *(const f4*)(sb + (j0+2)*Dv);
    f4 svn3 = *(const f4*)(sb + (j0+3)*Dv);

    #pragma unroll
    for (int jj = 0; jj < 32; jj += 4) {
        const int j4 = j0 + jj;
        const f4 sv0 = svn0, sv1 = svn1, sv2 = svn2, sv3 = svn3;
        if (jj < 28) {                 // compile-time under full unroll
            svn0 = *(const f4*)(sb + (j4+4)*Dv);
            svn1 = *(const f4*)(sb + (j4+5)*Dv);
            svn2 = *(const f4*)(sb + (j4+6)*Dv);
            svn3 = *(const f4*)(sb + (j4+7)*Dv);
        }
        f4 a[8];
        #pragma unroll
        for (int r = 0; r < 8; ++r)
            a[r] = *(const f4*)(&A_lds[r][j4]);   // b128 broadcast, free
        #pragma unroll
        for (int r = 0; r < 8; ++r) {
            acc[r] += a[r][0] * relu4(sv0 + tv[r]);
            acc[r] += a[r][1] * relu4(sv1 + tv[r]);
            acc[r] += a[r][2] * relu4(sv2 + tv[r]);
            acc[r] += a[r][3] * relu4(sv3 + tv[r]);
        }
    }

    // jg-partials -> LDS, reduce 16-way (256 threads; waves 4-7 idle briefly)
    #pragma unroll
    for (int r = 0; r < 8; ++r) part[jg][r][dq] = acc[r];
    __syncthreads();
    if (t < 256) {
        const int ri = t >> 5;         // 0..7
        f4 s = part[0][ri][dq];
        #pragma unroll
        for (int g = 1; g < 16; ++g) s += part[g][ri][dq];
        *(f4*)(&hsum[ri][dq*4]) = s;
    }
    __syncthreads();

    // epilogue: out = ES + hsum@W2 + b2; thread = (1 row rr, 2 cols c0,c0+1)
    const int cg = t & 63;
    const int rr = t >> 6;             // 0..7
    const int c0 = 2*cg;
    float o0 = b2[c0], o1 = b2[c0+1];
    #pragma unroll 8
    for (int k4 = 0; k4 < Dv; k4 += 4) {
        const f4 h = *(const f4*)(&hsum[rr][k4]);  // b128 broadcast
        #pragma unroll
        for (int u = 0; u < 4; ++u) {
            const float2 w = *(const float2*)(W2 + (k4 + u)*Dv + c0);
            o0 = fmaf(h[u], w.x, o0);
            o1 = fmaf(h[u], w.y, o1);
        }
    }
    const int ro = (b*Nv + i0 + rr)*Dv + c0;
    const float2 e = *(const float2*)(ES + ro);
    float2 v; v.x = e.x + o0; v.y = e.y + o1;
    *(float2*)(out + ro) = v;
}

extern "C" void kernel_launch(void* const* d_in, const int* in_sizes, int n_in,
                              void* d_out, int out_size, void* d_ws, size_t ws_size,
                              hipStream_t stream) {
    (void)in_sizes; (void)n_in; (void)out_size; (void)ws_size;
    const float* ES = (const float*)d_in[0];
    const float* Wp = (const float*)d_in[1];
    const float* bp = (const float*)d_in[2];
    const float* EL = (const float*)d_in[3];
    const float* W1 = (const float*)d_in[4];
    const float* b1 = (const float*)d_in[5];
    const float* W2 = (const float*)d_in[6];
    const float* b2 = (const float*)d_in[7];
    const float* UN = (const float*)d_in[8];

    float* out   = (float*)d_out;
    float* A_out = out + BND;            // A broadcast region: B*N*N floats

    float* s_buf = (float*)d_ws;         // s' = proj@W1_src + b1  (B*N*D)
    float* t_buf = s_buf + BND;          // t  = proj@W1_tgt       (B*N*D)

    k_prep<<<512, 256, 0, stream>>>(ES, Wp, bp, W1, b1, EL, UN,
                                    s_buf, t_buf, A_out);
    k_main<<<dim3(Nv/8, Bv), 512, 0, stream>>>(s_buf, t_buf, A_out, ES, W2, b2,
                                               out);
}